// Round 6
// baseline (309.488 us; speedup 1.0000x reference)
//
#include <hip/hip_runtime.h>
#include <hip/hip_bf16.h>
#include <math.h>

#define EPS 1e-5f
#define MAXN (1.0f - EPS)
#define MINN 1e-10f

constexpr int D = 2048;      // Dh == Din == 2048 for this problem

typedef unsigned short u16;
typedef __bf16 bf16x8 __attribute__((ext_vector_type(8)));
typedef float floatx4 __attribute__((ext_vector_type(4)));

// ---------- small helpers ----------

__device__ __forceinline__ u16 f2bf(float f) {
    union { float f; unsigned u; } v; v.f = f;
    unsigned r = v.u + 0x7FFFu + ((v.u >> 16) & 1u);   // RNE
    return (u16)(r >> 16);
}

__device__ __forceinline__ float bf2f(u16 b) {
    union { unsigned u; float f; } v; v.u = ((unsigned)b) << 16; return v.f;
}

// load 8 contiguous bf16 -> float[8] (one 16B load)
__device__ __forceinline__ void load_bf8(const u16* p, float* d) {
    uint4 r = *(const uint4*)p;
    unsigned w[4] = {r.x, r.y, r.z, r.w};
    #pragma unroll
    for (int i = 0; i < 4; ++i) {
        d[2 * i]     = bf2f((u16)(w[i] & 0xFFFFu));
        d[2 * i + 1] = bf2f((u16)(w[i] >> 16));
    }
}

// store float[8] -> 8 contiguous bf16 (one 16B store)
__device__ __forceinline__ void store_bf8(u16* p, const float* s) {
    u16 pk[8];
    #pragma unroll
    for (int i = 0; i < 8; ++i) pk[i] = f2bf(s[i]);
    *(uint4*)p = *(const uint4*)pk;
}

__device__ __forceinline__ void load_f8(const float* p, float* d) {
    *(float4*)(d)     = *(const float4*)(p);
    *(float4*)(d + 4) = *(const float4*)(p + 4);
}

__device__ __forceinline__ void store_f8(float* p, const float* s) {
    *(float4*)(p)     = *(const float4*)(s);
    *(float4*)(p + 4) = *(const float4*)(s + 4);
}

__device__ __forceinline__ float artanh_(float x) {
    x = fminf(fmaxf(x, -1.0f + EPS), 1.0f - EPS);
    return 0.5f * logf((1.0f + x) / (1.0f - x));
}

__device__ __forceinline__ float sigmoid_(float x) {
    return 1.0f / (1.0f + expf(-x));
}

// async global->LDS, 16 bytes/lane; lds base must be wave-uniform
__device__ __forceinline__ void gl_lds16(const u16* g, u16* l) {
    __builtin_amdgcn_global_load_lds(
        (const __attribute__((address_space(1))) unsigned int*)g,
        (__attribute__((address_space(3))) unsigned int*)l, 16, 0, 0);
}

// N simultaneous block-wide sums, ONE barrier pair. 256 threads / 4 waves.
template<int N>
__device__ __forceinline__ void block_sums(float* v, float* sbuf) {
    #pragma unroll
    for (int n = 0; n < N; ++n)
        #pragma unroll
        for (int off = 32; off >= 1; off >>= 1) v[n] += __shfl_xor(v[n], off, 64);
    int w = threadIdx.x >> 6;
    __syncthreads();                       // protect sbuf from previous call
    if ((threadIdx.x & 63) == 0) {
        #pragma unroll
        for (int n = 0; n < N; ++n) sbuf[w * N + n] = v[n];
    }
    __syncthreads();
    #pragma unroll
    for (int n = 0; n < N; ++n)
        v[n] = sbuf[n] + sbuf[N + n] + sbuf[2 * N + n] + sbuf[3 * N + n];
}

// finish mob_mat_mul: given |Mx|^2 and g = artanh(x_n)/x_n, return scale coef
// (out = coef * Mx_raw) and the output norm (post-proj).
__device__ __forceinline__ void mmm_finish(float sum2, float g, float* coef, float* onorm) {
    float mxn = sqrtf(fmaxf(sum2, MINN));
    float tt  = tanhf(mxn * g);
    float on  = fminf(tt, MAXN);
    *coef = on / mxn;
    *onorm = on;
}

// apply mob_add given duv already reduced. |num|^2 computed ANALYTICALLY:
// |cu*u + cv*v|^2 = cu^2 u2 + 2 cu cv duv + cv^2 v2  (no second reduction).
// u <- proj(mob_add(u,v)); returns post-proj norm.
__device__ __forceinline__ float mob_apply(float* u, const float* v,
                                           float u2, float v2, float duv) {
    float cu  = 1.f + 2.f * duv + v2;
    float cv  = 1.f - u2;
    float den = fmaxf(1.f + 2.f * duv + u2 * v2, MINN);
    float s2  = cu * cu * u2 + 2.f * cu * cv * duv + cv * cv * v2;
    float n   = sqrtf(fmaxf(s2 / (den * den), MINN));
    float sc  = ((n > MAXN) ? MAXN / n : 1.f) / den;
    #pragma unroll
    for (int i = 0; i < 8; ++i) u[i] = sc * (cu * u[i] + cv * v[i]);
    return fminf(n, MAXN);
}

// shared transpose-tile helper: one 64x64 f32->bf16T tile through LDS
__device__ __forceinline__ void trans_tile(const float* W, u16* Wt,
                                           int n0, int k0, float* tile) {
    int t = threadIdx.x;
    int lr = t >> 4, lc = (t & 15) * 4;
    #pragma unroll
    for (int p = 0; p < 4; ++p) {
        int r = lr + p * 16;
        float4 v = *(const float4*)(W + (size_t)(k0 + r) * D + n0 + lc);
        tile[r * 65 + lc + 0] = v.x;
        tile[r * 65 + lc + 1] = v.y;
        tile[r * 65 + lc + 2] = v.z;
        tile[r * 65 + lc + 3] = v.w;
    }
    __syncthreads();
    int wn = t >> 3, ws = (t & 7) * 8;
    #pragma unroll
    for (int p = 0; p < 2; ++p) {
        int n = wn + p * 32;
        u16 pk[8];
        #pragma unroll
        for (int j = 0; j < 8; ++j) pk[j] = f2bf(tile[(ws + j) * 65 + n]);
        *(uint4*)(Wt + (size_t)(n0 + n) * D + k0 + ws) = *(uint4*)pk;
    }
}

// ---------- K0: transpose 5 weights (z!=4) + input projection (z==4) ----------

struct PrepBatch {
    const float* W[5]; u16* Wt[5];
    const float* hx; const float* h;
    u16* hx_bf; u16* h_bf;
    float* g_x; float* g_h;
};

__global__ __launch_bounds__(256) void wtrans_prep(PrepBatch pb) {
    __shared__ float tile[64 * 65];        // transpose tile; first 8 reused as sbuf
    int t = threadIdx.x;

    if (blockIdx.z != 4) {
        int wi = (blockIdx.z == 5) ? 4 : blockIdx.z;
        trans_tile(pb.W[wi], pb.Wt[wi],
                   blockIdx.x * 64, blockIdx.y * 64, tile);
    } else {
        // projection: 1024 blocks here, each handles 2 rows
        int bid = blockIdx.y * (D / 64) + blockIdx.x;   // 0..1023
        for (int rr = 0; rr < 2; ++rr) {
            int b = bid * 2 + rr;
            size_t off = (size_t)b * D + t * 8;
            float xv[8], hv[8];
            load_f8(pb.hx + off, xv);
            load_f8(pb.h + off, hv);
            float s[2] = {0.f, 0.f};
            #pragma unroll
            for (int i = 0; i < 8; ++i) { s[0] += xv[i] * xv[i]; s[1] += hv[i] * hv[i]; }
            block_sums<2>(s, tile);

            float nx = sqrtf(fmaxf(s[0], MINN));
            float scx = (nx > MAXN) ? MAXN / nx : 1.0f;
            float nh = sqrtf(fmaxf(s[1], MINN));
            float sch = (nh > MAXN) ? MAXN / nh : 1.0f;
            #pragma unroll
            for (int i = 0; i < 8; ++i) { xv[i] *= scx; hv[i] *= sch; }
            store_bf8(pb.hx_bf + off, xv);
            store_bf8(pb.h_bf + off, hv);
            if (t == 0) {
                float xn = fminf(nx, MAXN), hn = fminf(nh, MAXN);
                pb.g_x[b] = artanh_(xn) / xn;
                pb.g_h[b] = artanh_(hn) / hn;
            }
        }
    }
}

// ---------- 128x128 GEMM core (r6: r2/r5 schedule at 2 blocks/CU) ----------
// C[M,N](bf16) = A[M,K](bf16) @ W[N,K](bf16)^T.
// BM=BN=128, BK=64 in two 32-k half-units. 256 threads = 4 waves (2x2 grid),
// wave tile 64x64, acc 4x4 floatx4. LDS ring {2 buf}x{2 khalf} per operand:
// unit = 128 rows x 32 k x 2B = 8 KB -> total 64 KB -> **2 blocks/CU**.
// r6 rationale: the 256^2 config (128 KB LDS) pinned occupancy to ONE block
// per CU, so all barrier/resync/prologue stalls were fully exposed (r3/r4/r5
// all stuck at ~5400 cyc/K-tile vs 2483 cyc of MFMA work). Two independent
// 4-wave barrier groups per CU let one block's MFMA fill the other's sync
// stalls (m114 mechanism). Barriers also drop 9 -> 4 per K-tile.
// Schedule per K-tile (2 phases, counted vmcnt, never 0):
//   ph0: read kk0 frags; stage A+B(k1,t+1); BAR; setprio1; 16 MFMA; setprio0; BAR
//   ph1: read kk1 frags; stage A+B(k0,t+2); BAR; setprio1; 16 MFMA; setprio0;
//        vmcnt(4); BAR
// Ledger: stages are 4 gl_lds each; at boundary of tile t the queue is
// [k0(t+1), k1(t+1), k0(t+2)] = 12 -> vmcnt(4) completes tile t+1, leaves
// k0(t+2) in flight. WAR: unit (bsel,0) re-staged in ph1 after the ph0 END
// barrier that follows its last reads; unit (bno,1) re-staged in ph0 after
// the t-1 boundary barrier that follows its last reads (t-1 ph1). RAW: k1(t)
// drained by t-1's boundary vmcnt(4); k0(t) drained one tile earlier.
// Swizzle (r2-verified, 0 SQ_LDS_BANK_CONFLICT): LDS slot s holds kseg
// s^((row>>1)&3); pre-swizzled global source, swizzled ds_read, linear
// gl_lds dest. 8-lane runs hit 16B-groups {0,4,1,5,2,6,3,7} on both the
// stage-write and frag-read sides -> conflict-free b128.

#define PHASE_MID() do { \
    __builtin_amdgcn_s_barrier(); \
    __builtin_amdgcn_s_setprio(1); } while (0)

#define PHASE_END() do { \
    __builtin_amdgcn_s_setprio(0); \
    __builtin_amdgcn_s_barrier(); } while (0)

template<int KLEN>
__device__ __forceinline__ void gemm128_body(const u16* __restrict__ A,
                                             const u16* __restrict__ W,
                                             u16* __restrict__ C, int koff,
                                             u16* As, u16* Ws) {
    constexpr int T  = KLEN / 64;       // K-tiles
    constexpr int U  = 4096;            // u16 per half-unit (128 rows x 32 k)

    int t0 = threadIdx.x;
    int wave = t0 >> 6, lane = t0 & 63, l16 = lane & 15, quad = lane >> 4;
    int wr = wave >> 1, wc = wave & 1;      // 2x2 wave grid
    int brow = blockIdx.y * 128, bcol = blockIdx.x * 128;

    // staging source (per-thread, pre-swizzled k-segment)
    int srow = t0 >> 2;                     // 0..63 per issue
    int sseg = (t0 & 3) ^ ((srow >> 1) & 3);
    const u16* srcA = A + (size_t)(brow + srow) * D + koff + sseg * 8;
    const u16* srcB = W + (size_t)(bcol + srow) * D + koff + sseg * 8;
    u16* ldsA = As + wave * 512;            // wave-uniform slices (1 KB/wave)
    u16* ldsB = Ws + wave * 512;

    auto stageA = [&](int buf, int kh, int tile) {
        const u16* s = srcA + tile * 64 + kh * 32;
        u16* d = ldsA + (buf * 2 + kh) * U;
        gl_lds16(s, d);
        gl_lds16(s + (size_t)64 * D, d + 2048);
    };
    auto stageB = [&](int buf, int kh, int tile) {
        const u16* s = srcB + tile * 64 + kh * 32;
        u16* d = ldsB + (buf * 2 + kh) * U;
        gl_lds16(s, d);
        gl_lds16(s + (size_t)64 * D, d + 2048);
    };

    // fragment-read bases (swizzled); unit (buf,kk): +(buf*2+kk)*U; frag i: +i*512
    const u16* aF = As + (wr * 64 + l16) * 32 + ((quad ^ ((l16 >> 1) & 3)) * 8);
    const u16* bF = Ws + (wc * 64 + l16) * 32 + ((quad ^ ((l16 >> 1) & 3)) * 8);

    floatx4 acc[4][4];
    #pragma unroll
    for (int i = 0; i < 4; ++i)
        #pragma unroll
        for (int j = 0; j < 4; ++j)
            #pragma unroll
            for (int e = 0; e < 4; ++e) acc[i][j][e] = 0.f;

    // prologue: tile0 complete + tile1 khalf0; drain tile0 (12 issued, leave 4)
    stageA(0, 0, 0); stageB(0, 0, 0);
    stageA(0, 1, 0); stageB(0, 1, 0);
    stageA(1, 0, 1); stageB(1, 0, 1);
    asm volatile("s_waitcnt vmcnt(4)" ::: "memory");
    __builtin_amdgcn_s_barrier();

    #pragma unroll 2
    for (int tt = 0; tt < T; ++tt) {
        int bsel = tt & 1, bno = bsel ^ 1;
        const u16* a0 = aF + (bsel * 2 + 0) * U;
        const u16* a1 = aF + (bsel * 2 + 1) * U;
        const u16* b0 = bF + (bsel * 2 + 0) * U;
        const u16* b1 = bF + (bsel * 2 + 1) * U;
        bool st1 = (tt + 1) < T, st2 = (tt + 2) < T;

        bf16x8 af[4], bf4[4];
        // ---- phase 0: kk=0 ----
        #pragma unroll
        for (int i = 0; i < 4; ++i) af[i]  = *(const bf16x8*)(a0 + i * 512);
        #pragma unroll
        for (int j = 0; j < 4; ++j) bf4[j] = *(const bf16x8*)(b0 + j * 512);
        if (st1) { stageA(bno, 1, tt + 1); stageB(bno, 1, tt + 1); }
        PHASE_MID();
        #pragma unroll
        for (int i = 0; i < 4; ++i)
            #pragma unroll
            for (int j = 0; j < 4; ++j)
                acc[i][j] = __builtin_amdgcn_mfma_f32_16x16x32_bf16(af[i], bf4[j], acc[i][j], 0, 0, 0);
        PHASE_END();
        // ---- phase 1: kk=1; tile boundary ----
        #pragma unroll
        for (int i = 0; i < 4; ++i) af[i]  = *(const bf16x8*)(a1 + i * 512);
        #pragma unroll
        for (int j = 0; j < 4; ++j) bf4[j] = *(const bf16x8*)(b1 + j * 512);
        if (st2) { stageA(bsel, 0, tt + 2); stageB(bsel, 0, tt + 2); }
        PHASE_MID();
        #pragma unroll
        for (int i = 0; i < 4; ++i)
            #pragma unroll
            for (int j = 0; j < 4; ++j)
                acc[i][j] = __builtin_amdgcn_mfma_f32_16x16x32_bf16(af[i], bf4[j], acc[i][j], 0, 0, 0);
        __builtin_amdgcn_s_setprio(0);
        asm volatile("s_waitcnt vmcnt(4)" ::: "memory");   // counted, not 0
        __builtin_amdgcn_s_barrier();
    }

    // epilogue: C layout col=lane&15, row=(lane>>4)*4+reg (16x16x32 bf16)
    #pragma unroll
    for (int i = 0; i < 4; ++i) {
        #pragma unroll
        for (int j = 0; j < 4; ++j) {
            int row = brow + wr * 64 + i * 16 + quad * 4;
            int col = bcol + wc * 64 + j * 16 + l16;
            #pragma unroll
            for (int r = 0; r < 4; ++r)
                C[(size_t)(row + r) * D + col] = f2bf(acc[i][j][r]);
        }
    }
}

// ---------- G1: 4 GEMMs (128x128 tiles, 2 blocks/CU) ----------

struct G1Batch { const u16* A[4]; const u16* W[4]; u16* C[4]; };

__global__ __launch_bounds__(256, 2) void g1_kernel(G1Batch gb) {
    __shared__ u16 As[16384];              // 32 KB
    __shared__ u16 Ws[16384];              // 32 KB  (64 KB total -> 2 blocks/CU)
    int z = blockIdx.z;
    gemm128_body<2048>(gb.A[z], gb.W[z], gb.C[z], 0, As, Ws);
}

// ---------- G2: 2-way K-split GEMM (128x128 tiles, 2 blocks/CU) ----------

struct GemmBatch { const u16* A[2]; const u16* W[2]; u16* C[2]; int koff[2]; };

__global__ __launch_bounds__(256, 2) void g2_kernel(GemmBatch gb) {
    __shared__ u16 As[16384];              // 32 KB
    __shared__ u16 Ws[16384];              // 32 KB
    int z = blockIdx.z;
    gemm128_body<1024>(gb.A[z], gb.W[z], gb.C[z], gb.koff[z], As, Ws);
}

// ---------- K4: fused middle (finish 4 matvecs, z, r, r_point_h) ----------

__global__ __launch_bounds__(256) void mid_kernel(
    const u16* __restrict__ c_wz, const u16* __restrict__ c_uz,
    const u16* __restrict__ c_wr, const u16* __restrict__ c_ur,
    const u16* __restrict__ h_bf,
    const float* __restrict__ g_x, const float* __restrict__ g_h,
    const float* __restrict__ b_z, const float* __restrict__ b_r,
    u16* __restrict__ z_out, u16* __restrict__ uxr_out,
    u16* __restrict__ rph_bf, float* __restrict__ g_rph) {
    __shared__ float sbuf[24];
    int b = blockIdx.x, t = threadIdx.x;
    size_t off = (size_t)b * D + t * 8;
    int cbase = t * 8;

    float wz[8], uz[8], wr2[8], ur2[8], hp[8], bz[8], br[8];
    load_bf8(c_wz + off, wz);
    load_bf8(c_uz + off, uz);
    load_bf8(c_wr + off, wr2);
    load_bf8(c_ur + off, ur2);
    load_bf8(h_bf + off, hp);
    load_f8(b_z + cbase, bz);
    load_f8(b_r + cbase, br);

    float s[6] = {0, 0, 0, 0, 0, 0};
    #pragma unroll
    for (int i = 0; i < 8; ++i) {
        s[0] += wz[i] * wz[i];  s[1] += uz[i] * uz[i];
        s[2] += wr2[i] * wr2[i]; s[3] += ur2[i] * ur2[i];
        s[4] += bz[i] * bz[i];  s[5] += br[i] * br[i];
    }
    block_sums<6>(s, sbuf);
    float gh = g_h[b], gx = g_x[b];

    float cwz, nwz, cuz, nuz, cwr, nwr, cur, nur;
    mmm_finish(s[0], gh, &cwz, &nwz);
    mmm_finish(s[1], gx, &cuz, &nuz);
    mmm_finish(s[2], gh, &cwr, &nwr);
    mmm_finish(s[3], gx, &cur, &nur);
    #pragma unroll
    for (int i = 0; i < 8; ++i) {
        wz[i] *= cwz; uz[i] *= cuz; wr2[i] *= cwr; ur2[i] *= cur;
    }
    float sbz = s[4], sbr2 = s[5];

    // z-chain and r-chain mob_add #1 (batched duv)
    float d[2] = {0.f, 0.f};
    #pragma unroll
    for (int i = 0; i < 8; ++i) { d[0] += wz[i] * uz[i]; d[1] += wr2[i] * ur2[i]; }
    block_sums<2>(d, sbuf);
    float n1z = mob_apply(wz, uz, nwz * nwz, nuz * nuz, d[0]);
    float n1r = mob_apply(wr2, ur2, nwr * nwr, nur * nur, d[1]);

    // mob_add #2 (+bias, batched duv)
    d[0] = 0.f; d[1] = 0.f;
    #pragma unroll
    for (int i = 0; i < 8; ++i) { d[0] += wz[i] * bz[i]; d[1] += wr2[i] * br[i]; }
    block_sums<2>(d, sbuf);
    float n2z = mob_apply(wz, bz, n1z * n1z, sbz, d[0]);
    float n2r = mob_apply(wr2, br, n1r * n1r, sbr2, d[1]);

    float gz = artanh_(n2z) / n2z;
    float gr = artanh_(n2r) / n2r;
    float zz[8], v[8];
    float sv = 0.f;
    #pragma unroll
    for (int i = 0; i < 8; ++i) {
        zz[i] = sigmoid_(gz * wz[i]);
        float r = sigmoid_(gr * wr2[i]);
        v[i] = gh * hp[i] * r;            // log_map_zero(h) * r
        sv += v[i] * v[i];
    }
    store_bf8(z_out + off, zz);
    block_sums<1>(&sv, sbuf);
    float nv = sqrtf(fmaxf(sv, MINN));
    float th = fminf(tanhf(nv), MAXN);
    float cr = th / nv;
    #pragma unroll
    for (int i = 0; i < 8; ++i) v[i] *= cr;
    store_bf8(rph_bf + off, v);
    store_bf8(uxr_out + off, ur2);        // finished UxR (reused for h_tilde)
    if (t == 0) g_rph[b] = artanh_(th) / th;
}

// ---------- K6: epilogue ----------

__global__ __launch_bounds__(256) void fin_kernel(
    const u16* __restrict__ p0, const u16* __restrict__ p1,
    const u16* __restrict__ uxr, const u16* __restrict__ z_in,
    const u16* __restrict__ h_bf,
    const float* __restrict__ g_rph, const float* __restrict__ b_h,
    float* __restrict__ out) {
    __shared__ float sbuf[16];
    int b = blockIdx.x, t = threadIdx.x;
    size_t off = (size_t)b * D + t * 8;
    int cbase = t * 8;

    float wh[8], ux[8], zz[8], hp[8], bh[8], t0[8];
    load_bf8(p0 + off, wh);
    load_bf8(p1 + off, t0);
    #pragma unroll
    for (int i = 0; i < 8; ++i) wh[i] += t0[i];   // K-split partials
    load_bf8(uxr + off, ux);
    load_bf8(z_in + off, zz);
    load_bf8(h_bf + off, hp);
    load_f8(b_h + cbase, bh);

    float s[4] = {0, 0, 0, 0};
    #pragma unroll
    for (int i = 0; i < 8; ++i) {
        s[0] += wh[i] * wh[i]; s[1] += ux[i] * ux[i];
        s[2] += hp[i] * hp[i]; s[3] += bh[i] * bh[i];
    }
    block_sums<4>(s, sbuf);
    float swh = s[0], sux = s[1], shp = s[2], sbh = s[3];

    float cwh, nwh;
    mmm_finish(swh, g_rph[b], &cwh, &nwh);
    #pragma unroll
    for (int i = 0; i < 8; ++i) wh[i] *= cwh;

    // h_tilde = mob_add(mob_add(WhH, UxR), b_h)
    float d = 0.f;
    #pragma unroll
    for (int i = 0; i < 8; ++i) d += wh[i] * ux[i];
    block_sums<1>(&d, sbuf);
    float n1 = mob_apply(wh, ux, nwh * nwh, sux, d);

    d = 0.f;
    #pragma unroll
    for (int i = 0; i < 8; ++i) d += wh[i] * bh[i];
    block_sums<1>(&d, sbuf);
    float nht = mob_apply(wh, bh, n1 * n1, sbh, d);

    // minus = mob_add(-h_proj, h_tilde)
    #pragma unroll
    for (int i = 0; i < 8; ++i) ux[i] = -hp[i];   // reuse ux
    d = 0.f;
    #pragma unroll
    for (int i = 0; i < 8; ++i) d += ux[i] * wh[i];
    block_sums<1>(&d, sbuf);
    float nm = mob_apply(ux, wh, shp, nht * nht, d);

    // emz = exp_map_zero(log_map_zero(minus) * z)
    float lm = artanh_(nm) / nm;
    float sv = 0.f;
    #pragma unroll
    for (int i = 0; i < 8; ++i) {
        float v = lm * ux[i] * zz[i];
        ux[i] = v;
        sv += v * v;
    }
    block_sums<1>(&sv, sbuf);
    float nv = sqrtf(fmaxf(sv, MINN));
    float th = fminf(tanhf(nv), MAXN);
    float ce = th / nv;
    #pragma unroll
    for (int i = 0; i < 8; ++i) ux[i] *= ce;

    // new_h = mob_add(h_proj, emz)
    d = 0.f;
    #pragma unroll
    for (int i = 0; i < 8; ++i) d += hp[i] * ux[i];
    block_sums<1>(&d, sbuf);
    mob_apply(hp, ux, shp, th * th, d);
    store_f8(out + off, hp);
}

// ---------- launch ----------

extern "C" void kernel_launch(void* const* d_in, const int* in_sizes, int n_in,
                              void* d_out, int out_size, void* d_ws, size_t ws_size,
                              hipStream_t stream) {
    const float* hyp_x  = (const float*)d_in[0];
    const float* hidden = (const float*)d_in[1];
    const float* w_z = (const float*)d_in[2];
    const float* w_r = (const float*)d_in[3];
    const float* w_h = (const float*)d_in[4];
    const float* u_z = (const float*)d_in[5];
    const float* u_r = (const float*)d_in[6];
    const float* b_z = (const float*)d_in[7];
    const float* b_r = (const float*)d_in[8];
    const float* b_h = (const float*)d_in[9];
    float* out = (float*)d_out;

    int B = in_sizes[1] / D;   // 2048

    char* ws = (char*)d_ws;
    size_t o = 0;
    auto alloc = [&](size_t bytes) -> void* {
        void* p = ws + o;
        o += (bytes + 255) & ~(size_t)255;
        return p;
    };
    u16* wt[5];   // 0=w_z,1=w_r,2=w_h,3=u_z,4=u_r (transposed bf16 [N][K])
    for (int i = 0; i < 5; ++i) wt[i] = (u16*)alloc((size_t)D * D * 2);
    u16* hx_bf = (u16*)alloc((size_t)B * D * 2);
    u16* h_bf  = (u16*)alloc((size_t)B * D * 2);
    float* g_x   = (float*)alloc((size_t)B * 4);
    float* g_h   = (float*)alloc((size_t)B * 4);
    float* g_rph = (float*)alloc((size_t)B * 4);
    u16* cz0 = (u16*)alloc((size_t)B * D * 2);   // G1 outputs, bf16
    u16* cz1 = (u16*)alloc((size_t)B * D * 2);
    u16* cz2 = (u16*)alloc((size_t)B * D * 2);
    u16* cz3 = (u16*)alloc((size_t)B * D * 2);
    u16* p0 = (u16*)alloc((size_t)B * D * 2);    // G2 K-partials, bf16
    u16* p1 = (u16*)alloc((size_t)B * D * 2);
    u16* z_buf = (u16*)alloc((size_t)B * D * 2);
    u16* uxr = (u16*)alloc((size_t)B * D * 2);
    u16* rph = (u16*)alloc((size_t)B * D * 2);

    // K0: transpose all 5 weights (z!=4) + projection (z==4)
    PrepBatch pb;
    pb.W[0] = w_z; pb.Wt[0] = wt[0];
    pb.W[1] = w_r; pb.Wt[1] = wt[1];
    pb.W[2] = u_z; pb.Wt[2] = wt[3];
    pb.W[3] = u_r; pb.Wt[3] = wt[4];
    pb.W[4] = w_h; pb.Wt[4] = wt[2];
    pb.hx = hyp_x; pb.h = hidden;
    pb.hx_bf = hx_bf; pb.h_bf = h_bf;
    pb.g_x = g_x; pb.g_h = g_h;
    wtrans_prep<<<dim3(D / 64, D / 64, 6), 256, 0, stream>>>(pb);

    // G1: 4 GEMMs, 128x128 tiles, 4 waves, 2 blocks/CU (1024 wgs = 4/CU)
    G1Batch g1;
    g1.A[0] = h_bf;  g1.W[0] = wt[0]; g1.C[0] = cz0;
    g1.A[1] = hx_bf; g1.W[1] = wt[3]; g1.C[1] = cz1;
    g1.A[2] = h_bf;  g1.W[2] = wt[1]; g1.C[2] = cz2;
    g1.A[3] = hx_bf; g1.W[3] = wt[4]; g1.C[3] = cz3;
    g1_kernel<<<dim3(D / 128, B / 128, 4), 256, 0, stream>>>(g1);

    // K4: middle fusion
    mid_kernel<<<dim3(B), 256, 0, stream>>>(cz0, cz1, cz2, cz3, h_bf, g_x, g_h,
                                            b_z, b_r, z_buf, uxr, rph, g_rph);

    // G2: 2-way K-split r_point_h @ w_h -> bf16 partials p0,p1 (512 wgs = 2/CU)
    GemmBatch g2;
    g2.A[0] = rph; g2.W[0] = wt[2]; g2.C[0] = p0; g2.koff[0] = 0;
    g2.A[1] = rph; g2.W[1] = wt[2]; g2.C[1] = p1; g2.koff[1] = 1024;
    g2_kernel<<<dim3(D / 128, B / 128, 2), 256, 0, stream>>>(g2);

    // K6: epilogue (sums the two K-partials of Wh @ r_point_h)
    fin_kernel<<<dim3(B), 256, 0, stream>>>(p0, p1, uxr, z_buf, h_bf,
                                            g_rph, b_h, out);
}

// Round 7
// 296.856 us; speedup vs baseline: 1.0426x; 1.0426x over previous
//
#include <hip/hip_runtime.h>
#include <hip/hip_bf16.h>
#include <math.h>

#define EPS 1e-5f
#define MAXN (1.0f - EPS)
#define MINN 1e-10f

constexpr int D = 2048;      // Dh == Din == 2048 for this problem

typedef unsigned short u16;
typedef __bf16 bf16x8 __attribute__((ext_vector_type(8)));
typedef float floatx4 __attribute__((ext_vector_type(4)));

// ---------- small helpers ----------

__device__ __forceinline__ u16 f2bf(float f) {
    union { float f; unsigned u; } v; v.f = f;
    unsigned r = v.u + 0x7FFFu + ((v.u >> 16) & 1u);   // RNE
    return (u16)(r >> 16);
}

__device__ __forceinline__ float bf2f(u16 b) {
    union { unsigned u; float f; } v; v.u = ((unsigned)b) << 16; return v.f;
}

// load 8 contiguous bf16 -> float[8] (one 16B load)
__device__ __forceinline__ void load_bf8(const u16* p, float* d) {
    uint4 r = *(const uint4*)p;
    unsigned w[4] = {r.x, r.y, r.z, r.w};
    #pragma unroll
    for (int i = 0; i < 4; ++i) {
        d[2 * i]     = bf2f((u16)(w[i] & 0xFFFFu));
        d[2 * i + 1] = bf2f((u16)(w[i] >> 16));
    }
}

// store float[8] -> 8 contiguous bf16 (one 16B store)
__device__ __forceinline__ void store_bf8(u16* p, const float* s) {
    u16 pk[8];
    #pragma unroll
    for (int i = 0; i < 8; ++i) pk[i] = f2bf(s[i]);
    *(uint4*)p = *(const uint4*)pk;
}

__device__ __forceinline__ void load_f8(const float* p, float* d) {
    *(float4*)(d)     = *(const float4*)(p);
    *(float4*)(d + 4) = *(const float4*)(p + 4);
}

__device__ __forceinline__ void store_f8(float* p, const float* s) {
    *(float4*)(p)     = *(const float4*)(s);
    *(float4*)(p + 4) = *(const float4*)(s + 4);
}

__device__ __forceinline__ float artanh_(float x) {
    x = fminf(fmaxf(x, -1.0f + EPS), 1.0f - EPS);
    return 0.5f * logf((1.0f + x) / (1.0f - x));
}

__device__ __forceinline__ float sigmoid_(float x) {
    return 1.0f / (1.0f + expf(-x));
}

// async global->LDS, 16 bytes/lane; lds base must be wave-uniform
__device__ __forceinline__ void gl_lds16(const u16* g, u16* l) {
    __builtin_amdgcn_global_load_lds(
        (const __attribute__((address_space(1))) unsigned int*)g,
        (__attribute__((address_space(3))) unsigned int*)l, 16, 0, 0);
}

// N simultaneous block-wide sums, ONE barrier pair. 256 threads / 4 waves.
template<int N>
__device__ __forceinline__ void block_sums(float* v, float* sbuf) {
    #pragma unroll
    for (int n = 0; n < N; ++n)
        #pragma unroll
        for (int off = 32; off >= 1; off >>= 1) v[n] += __shfl_xor(v[n], off, 64);
    int w = threadIdx.x >> 6;
    __syncthreads();                       // protect sbuf from previous call
    if ((threadIdx.x & 63) == 0) {
        #pragma unroll
        for (int n = 0; n < N; ++n) sbuf[w * N + n] = v[n];
    }
    __syncthreads();
    #pragma unroll
    for (int n = 0; n < N; ++n)
        v[n] = sbuf[n] + sbuf[N + n] + sbuf[2 * N + n] + sbuf[3 * N + n];
}

// finish mob_mat_mul: given |Mx|^2 and g = artanh(x_n)/x_n, return scale coef
// (out = coef * Mx_raw) and the output norm (post-proj).
__device__ __forceinline__ void mmm_finish(float sum2, float g, float* coef, float* onorm) {
    float mxn = sqrtf(fmaxf(sum2, MINN));
    float tt  = tanhf(mxn * g);
    float on  = fminf(tt, MAXN);
    *coef = on / mxn;
    *onorm = on;
}

// apply mob_add given duv already reduced. |num|^2 computed ANALYTICALLY:
// |cu*u + cv*v|^2 = cu^2 u2 + 2 cu cv duv + cv^2 v2  (no second reduction).
// u <- proj(mob_add(u,v)); returns post-proj norm.
__device__ __forceinline__ float mob_apply(float* u, const float* v,
                                           float u2, float v2, float duv) {
    float cu  = 1.f + 2.f * duv + v2;
    float cv  = 1.f - u2;
    float den = fmaxf(1.f + 2.f * duv + u2 * v2, MINN);
    float s2  = cu * cu * u2 + 2.f * cu * cv * duv + cv * cv * v2;
    float n   = sqrtf(fmaxf(s2 / (den * den), MINN));
    float sc  = ((n > MAXN) ? MAXN / n : 1.f) / den;
    #pragma unroll
    for (int i = 0; i < 8; ++i) u[i] = sc * (cu * u[i] + cv * v[i]);
    return fminf(n, MAXN);
}

// shared transpose-tile helper: one 64x64 f32->bf16T tile through LDS
__device__ __forceinline__ void trans_tile(const float* W, u16* Wt,
                                           int n0, int k0, float* tile) {
    int t = threadIdx.x;
    int lr = t >> 4, lc = (t & 15) * 4;
    #pragma unroll
    for (int p = 0; p < 4; ++p) {
        int r = lr + p * 16;
        float4 v = *(const float4*)(W + (size_t)(k0 + r) * D + n0 + lc);
        tile[r * 65 + lc + 0] = v.x;
        tile[r * 65 + lc + 1] = v.y;
        tile[r * 65 + lc + 2] = v.z;
        tile[r * 65 + lc + 3] = v.w;
    }
    __syncthreads();
    int wn = t >> 3, ws = (t & 7) * 8;
    #pragma unroll
    for (int p = 0; p < 2; ++p) {
        int n = wn + p * 32;
        u16 pk[8];
        #pragma unroll
        for (int j = 0; j < 8; ++j) pk[j] = f2bf(tile[(ws + j) * 65 + n]);
        *(uint4*)(Wt + (size_t)(n0 + n) * D + k0 + ws) = *(uint4*)pk;
    }
}

// ---------- K0: transpose 5 weights (z!=4) + input projection (z==4) ----------

struct PrepBatch {
    const float* W[5]; u16* Wt[5];
    const float* hx; const float* h;
    u16* hx_bf; u16* h_bf;
    float* g_x; float* g_h;
};

__global__ __launch_bounds__(256) void wtrans_prep(PrepBatch pb) {
    __shared__ float tile[64 * 65];        // transpose tile; first 8 reused as sbuf
    int t = threadIdx.x;

    if (blockIdx.z != 4) {
        int wi = (blockIdx.z == 5) ? 4 : blockIdx.z;
        trans_tile(pb.W[wi], pb.Wt[wi],
                   blockIdx.x * 64, blockIdx.y * 64, tile);
    } else {
        // projection: 1024 blocks here, each handles 2 rows
        int bid = blockIdx.y * (D / 64) + blockIdx.x;   // 0..1023
        for (int rr = 0; rr < 2; ++rr) {
            int b = bid * 2 + rr;
            size_t off = (size_t)b * D + t * 8;
            float xv[8], hv[8];
            load_f8(pb.hx + off, xv);
            load_f8(pb.h + off, hv);
            float s[2] = {0.f, 0.f};
            #pragma unroll
            for (int i = 0; i < 8; ++i) { s[0] += xv[i] * xv[i]; s[1] += hv[i] * hv[i]; }
            block_sums<2>(s, tile);

            float nx = sqrtf(fmaxf(s[0], MINN));
            float scx = (nx > MAXN) ? MAXN / nx : 1.0f;
            float nh = sqrtf(fmaxf(s[1], MINN));
            float sch = (nh > MAXN) ? MAXN / nh : 1.0f;
            #pragma unroll
            for (int i = 0; i < 8; ++i) { xv[i] *= scx; hv[i] *= sch; }
            store_bf8(pb.hx_bf + off, xv);
            store_bf8(pb.h_bf + off, hv);
            if (t == 0) {
                float xn = fminf(nx, MAXN), hn = fminf(nh, MAXN);
                pb.g_x[b] = artanh_(xn) / xn;
                pb.g_h[b] = artanh_(hn) / hn;
            }
        }
    }
}

// ---------- 256-wide GEMM core (r5 schedule, best-known: g1 72.3us) ----------
// C[M,N](bf16) = A[M,K](bf16) @ W[N,K](bf16)^T.
// BM=256, BN = NJ*64 (NJ=4 -> 256, NJ=2 -> 128), BK=64 split into two
// 32-k half-units. LDS ring: {2 buf} x {2 khalf} per operand.
// 512 threads = 8 waves (2M x 4N), per-wave output 128 x NJ*16.
// Phase = {frag ds_reads; stage; BAR; setprio1; 16 MFMA; setprio0; BAR}.
// Compiler-managed lgkmcnt (fine-grained per-MFMA waits); counted
// vmcnt(4|3) once per K-tile, never 0. Stages: ph0:A(k1,t+1) ph1:B(k1,t+1)
// ph2:A(k0,t+2) ph3:B(k0,t+2).
// Swizzle (verified 0 SQ_LDS_BANK_CONFLICT): LDS slot s holds kseg
// s^((row>>1)&3); pre-swizzled global source, swizzled ds_read, linear
// gl_lds dest. NOTE (r1/r4 errata): s = quad^(row&3) and the 32x32
// fragment geometry both produce 6.3M conflicts — do not regress to them.

#define PHASE_MID() do { \
    __builtin_amdgcn_s_barrier(); \
    __builtin_amdgcn_s_setprio(1); } while (0)

#define PHASE_END() do { \
    __builtin_amdgcn_s_setprio(0); \
    __builtin_amdgcn_s_barrier(); } while (0)

template<int KLEN, int NJ>
__device__ __forceinline__ void gemm256_body(const u16* __restrict__ A,
                                             const u16* __restrict__ W,
                                             u16* __restrict__ C, int koff,
                                             u16* As, u16* Ws) {
    constexpr int T  = KLEN / 64;       // K-tiles
    constexpr int BN = NJ * 64;
    constexpr int AU = 8192;            // u16 per A half-unit (256 rows x 32 k)
    constexpr int BU = BN * 32;         // u16 per B half-unit

    int t0 = threadIdx.x;
    int wave = t0 >> 6, lane = t0 & 63, l16 = lane & 15, quad = lane >> 4;
    int wr = wave >> 2, wc = wave & 3;      // 2x4 wave grid
    int brow = blockIdx.y * 256, bcol = blockIdx.x * BN;

    // staging source (per-thread, pre-swizzled k-segment)
    int srow = t0 >> 2;                     // 0..127 per issue
    int sseg = (t0 & 3) ^ ((srow >> 1) & 3);
    const u16* srcA = A + (size_t)(brow + srow) * D + koff + sseg * 8;
    const u16* srcB = W + (size_t)(bcol + srow) * D + koff + sseg * 8;
    u16* ldsA = As + wave * 512;            // wave-uniform slices
    u16* ldsB = Ws + wave * 512;

    auto stageA = [&](int buf, int kh, int tile) {
        const u16* s = srcA + tile * 64 + kh * 32;
        u16* d = ldsA + (buf * 2 + kh) * AU;
        gl_lds16(s, d);
        gl_lds16(s + (size_t)128 * D, d + 4096);
    };
    auto stageB = [&](int buf, int kh, int tile) {
        const u16* s = srcB + tile * 64 + kh * 32;
        u16* d = ldsB + (buf * 2 + kh) * BU;
        gl_lds16(s, d);
        if constexpr (NJ == 4) gl_lds16(s + (size_t)128 * D, d + 4096);
    };

    // fragment-read bases (swizzled); frag (buf,kk,i): +(buf*2+kk)*AU + i*512
    const u16* aF = As + (wr * 128 + l16) * 32 + ((quad ^ ((l16 >> 1) & 3)) * 8);
    const u16* bF = Ws + (wc * (NJ * 16) + l16) * 32 + ((quad ^ ((l16 >> 1) & 3)) * 8);

    floatx4 acc[8][NJ];
    #pragma unroll
    for (int i = 0; i < 8; ++i)
        #pragma unroll
        for (int j = 0; j < NJ; ++j)
            #pragma unroll
            for (int e = 0; e < 4; ++e) acc[i][j][e] = 0.f;

    // prologue: tile0 complete + tile1 khalf0; wait so tile0 landed
    stageA(0, 0, 0); stageB(0, 0, 0);
    stageA(0, 1, 0); stageB(0, 1, 0);
    stageA(1, 0, 1); stageB(1, 0, 1);
    if constexpr (NJ == 4) asm volatile("s_waitcnt vmcnt(4)" ::: "memory");
    else                   asm volatile("s_waitcnt vmcnt(3)" ::: "memory");
    __builtin_amdgcn_s_barrier();

    #pragma unroll 2
    for (int tt = 0; tt < T; ++tt) {
        int bsel = tt & 1, bno = bsel ^ 1;
        const u16* aT = aF + bsel * (2 * AU);
        const u16* bT = bF + bsel * (2 * BU);
        bool st1 = (tt + 1) < T, st2 = (tt + 2) < T;

        if constexpr (NJ == 4) {
            bf16x8 bfr[4], afr[4];
            // ---- phase 0: kk=0, wave rows 0-63 ----
            #pragma unroll
            for (int j = 0; j < 4; ++j) bfr[j] = *(const bf16x8*)(bT + j * 512);
            #pragma unroll
            for (int i = 0; i < 4; ++i) afr[i] = *(const bf16x8*)(aT + i * 512);
            if (st1) stageA(bno, 1, tt + 1);
            PHASE_MID();
            #pragma unroll
            for (int i = 0; i < 4; ++i)
                #pragma unroll
                for (int j = 0; j < 4; ++j)
                    acc[i][j] = __builtin_amdgcn_mfma_f32_16x16x32_bf16(afr[i], bfr[j], acc[i][j], 0, 0, 0);
            PHASE_END();
            // ---- phase 1: kk=0, wave rows 64-127 (B frags reused) ----
            #pragma unroll
            for (int i = 0; i < 4; ++i) afr[i] = *(const bf16x8*)(aT + (4 + i) * 512);
            if (st1) stageB(bno, 1, tt + 1);
            PHASE_MID();
            #pragma unroll
            for (int i = 0; i < 4; ++i)
                #pragma unroll
                for (int j = 0; j < 4; ++j)
                    acc[4 + i][j] = __builtin_amdgcn_mfma_f32_16x16x32_bf16(afr[i], bfr[j], acc[4 + i][j], 0, 0, 0);
            PHASE_END();
            // ---- phase 2: kk=1, wave rows 0-63 ----
            #pragma unroll
            for (int j = 0; j < 4; ++j) bfr[j] = *(const bf16x8*)(bT + BU + j * 512);
            #pragma unroll
            for (int i = 0; i < 4; ++i) afr[i] = *(const bf16x8*)(aT + AU + i * 512);
            if (st2) stageA(bsel, 0, tt + 2);
            PHASE_MID();
            #pragma unroll
            for (int i = 0; i < 4; ++i)
                #pragma unroll
                for (int j = 0; j < 4; ++j)
                    acc[i][j] = __builtin_amdgcn_mfma_f32_16x16x32_bf16(afr[i], bfr[j], acc[i][j], 0, 0, 0);
            PHASE_END();
            // ---- phase 3: kk=1, wave rows 64-127; tile boundary ----
            #pragma unroll
            for (int i = 0; i < 4; ++i) afr[i] = *(const bf16x8*)(aT + AU + (4 + i) * 512);
            if (st2) stageB(bsel, 0, tt + 2);
            PHASE_MID();
            #pragma unroll
            for (int i = 0; i < 4; ++i)
                #pragma unroll
                for (int j = 0; j < 4; ++j)
                    acc[4 + i][j] = __builtin_amdgcn_mfma_f32_16x16x32_bf16(afr[i], bfr[j], acc[4 + i][j], 0, 0, 0);
            __builtin_amdgcn_s_setprio(0);
            asm volatile("s_waitcnt vmcnt(4)" ::: "memory");   // counted, not 0
            __builtin_amdgcn_s_barrier();
        } else {
            bf16x8 bfr[2], afr[8];
            // ---- phase 0: kk=0 ----
            #pragma unroll
            for (int j = 0; j < 2; ++j) bfr[j] = *(const bf16x8*)(bT + j * 512);
            #pragma unroll
            for (int i = 0; i < 8; ++i) afr[i] = *(const bf16x8*)(aT + i * 512);
            if (st1) { stageA(bno, 1, tt + 1); stageB(bno, 1, tt + 1); }
            PHASE_MID();
            #pragma unroll
            for (int i = 0; i < 8; ++i)
                #pragma unroll
                for (int j = 0; j < 2; ++j)
                    acc[i][j] = __builtin_amdgcn_mfma_f32_16x16x32_bf16(afr[i], bfr[j], acc[i][j], 0, 0, 0);
            PHASE_END();
            // ---- phase 1: kk=1; tile boundary ----
            #pragma unroll
            for (int j = 0; j < 2; ++j) bfr[j] = *(const bf16x8*)(bT + BU + j * 512);
            #pragma unroll
            for (int i = 0; i < 8; ++i) afr[i] = *(const bf16x8*)(aT + AU + i * 512);
            if (st2) { stageA(bsel, 0, tt + 2); stageB(bsel, 0, tt + 2); }
            PHASE_MID();
            #pragma unroll
            for (int i = 0; i < 8; ++i)
                #pragma unroll
                for (int j = 0; j < 2; ++j)
                    acc[i][j] = __builtin_amdgcn_mfma_f32_16x16x32_bf16(afr[i], bfr[j], acc[i][j], 0, 0, 0);
            __builtin_amdgcn_s_setprio(0);
            asm volatile("s_waitcnt vmcnt(3)" ::: "memory");   // counted, not 0
            __builtin_amdgcn_s_barrier();
        }
    }

    // epilogue: C layout col=lane&15, row=(lane>>4)*4+reg (16x16x32 bf16)
    #pragma unroll
    for (int i = 0; i < 8; ++i) {
        #pragma unroll
        for (int j = 0; j < NJ; ++j) {
            int row = brow + wr * 128 + i * 16 + quad * 4;
            int col = bcol + wc * (NJ * 16) + j * 16 + l16;
            #pragma unroll
            for (int r = 0; r < 4; ++r)
                C[(size_t)(row + r) * D + col] = f2bf(acc[i][j][r]);
        }
    }
}

// ---------- G1: 4 GEMMs (256x256 tiles) ----------

struct G1Batch { const u16* A[4]; const u16* W[4]; u16* C[4]; };

__global__ __launch_bounds__(512, 2) void g1_kernel(G1Batch gb) {
    __shared__ u16 As[32768];              // 64 KB
    __shared__ u16 Ws[32768];              // 64 KB  (128 KB total)
    int z = blockIdx.z;
    gemm256_body<2048, 4>(gb.A[z], gb.W[z], gb.C[z], 0, As, Ws);
}

// ---------- G2: 2-way K-split GEMM (256x128 tiles) ----------

struct GemmBatch { const u16* A[2]; const u16* W[2]; u16* C[2]; int koff[2]; };

__global__ __launch_bounds__(512, 2) void g2_kernel(GemmBatch gb) {
    __shared__ u16 As[32768];              // 64 KB
    __shared__ u16 Ws[16384];              // 32 KB  (96 KB total)
    int z = blockIdx.z;
    gemm256_body<1024, 2>(gb.A[z], gb.W[z], gb.C[z], gb.koff[z], As, Ws);
}

// ---------- K4: fused middle (finish 4 matvecs, z, r, r_point_h) ----------
// r7: outputs ALIAS inputs (z_out==c_wz, uxr_out==c_uz, rph_bf==c_wr).
// Safe: each thread loads all its inputs into registers before its first
// barrier; every store targets exactly the 8-element slot that only this
// thread read; cross-thread reads of those slots all precede the collective
// sync points that precede the stores.

__global__ __launch_bounds__(256) void mid_kernel(
    const u16* __restrict__ c_wz, const u16* __restrict__ c_uz,
    const u16* __restrict__ c_wr, const u16* __restrict__ c_ur,
    const u16* __restrict__ h_bf,
    const float* __restrict__ g_x, const float* __restrict__ g_h,
    const float* __restrict__ b_z, const float* __restrict__ b_r,
    u16* __restrict__ z_out, u16* __restrict__ uxr_out,
    u16* __restrict__ rph_bf, float* __restrict__ g_rph) {
    __shared__ float sbuf[24];
    int b = blockIdx.x, t = threadIdx.x;
    size_t off = (size_t)b * D + t * 8;
    int cbase = t * 8;

    float wz[8], uz[8], wr2[8], ur2[8], hp[8], bz[8], br[8];
    load_bf8(c_wz + off, wz);
    load_bf8(c_uz + off, uz);
    load_bf8(c_wr + off, wr2);
    load_bf8(c_ur + off, ur2);
    load_bf8(h_bf + off, hp);
    load_f8(b_z + cbase, bz);
    load_f8(b_r + cbase, br);

    float s[6] = {0, 0, 0, 0, 0, 0};
    #pragma unroll
    for (int i = 0; i < 8; ++i) {
        s[0] += wz[i] * wz[i];  s[1] += uz[i] * uz[i];
        s[2] += wr2[i] * wr2[i]; s[3] += ur2[i] * ur2[i];
        s[4] += bz[i] * bz[i];  s[5] += br[i] * br[i];
    }
    block_sums<6>(s, sbuf);
    float gh = g_h[b], gx = g_x[b];

    float cwz, nwz, cuz, nuz, cwr, nwr, cur, nur;
    mmm_finish(s[0], gh, &cwz, &nwz);
    mmm_finish(s[1], gx, &cuz, &nuz);
    mmm_finish(s[2], gh, &cwr, &nwr);
    mmm_finish(s[3], gx, &cur, &nur);
    #pragma unroll
    for (int i = 0; i < 8; ++i) {
        wz[i] *= cwz; uz[i] *= cuz; wr2[i] *= cwr; ur2[i] *= cur;
    }
    float sbz = s[4], sbr2 = s[5];

    // z-chain and r-chain mob_add #1 (batched duv)
    float d[2] = {0.f, 0.f};
    #pragma unroll
    for (int i = 0; i < 8; ++i) { d[0] += wz[i] * uz[i]; d[1] += wr2[i] * ur2[i]; }
    block_sums<2>(d, sbuf);
    float n1z = mob_apply(wz, uz, nwz * nwz, nuz * nuz, d[0]);
    float n1r = mob_apply(wr2, ur2, nwr * nwr, nur * nur, d[1]);

    // mob_add #2 (+bias, batched duv)
    d[0] = 0.f; d[1] = 0.f;
    #pragma unroll
    for (int i = 0; i < 8; ++i) { d[0] += wz[i] * bz[i]; d[1] += wr2[i] * br[i]; }
    block_sums<2>(d, sbuf);
    float n2z = mob_apply(wz, bz, n1z * n1z, sbz, d[0]);
    float n2r = mob_apply(wr2, br, n1r * n1r, sbr2, d[1]);

    float gz = artanh_(n2z) / n2z;
    float gr = artanh_(n2r) / n2r;
    float zz[8], v[8];
    float sv = 0.f;
    #pragma unroll
    for (int i = 0; i < 8; ++i) {
        zz[i] = sigmoid_(gz * wz[i]);
        float r = sigmoid_(gr * wr2[i]);
        v[i] = gh * hp[i] * r;            // log_map_zero(h) * r
        sv += v[i] * v[i];
    }
    store_bf8(z_out + off, zz);
    block_sums<1>(&sv, sbuf);
    float nv = sqrtf(fmaxf(sv, MINN));
    float th = fminf(tanhf(nv), MAXN);
    float cr = th / nv;
    #pragma unroll
    for (int i = 0; i < 8; ++i) v[i] *= cr;
    store_bf8(rph_bf + off, v);
    store_bf8(uxr_out + off, ur2);        // finished UxR (reused for h_tilde)
    if (t == 0) g_rph[b] = artanh_(th) / th;
}

// ---------- K6: epilogue ----------

__global__ __launch_bounds__(256) void fin_kernel(
    const u16* __restrict__ p0, const u16* __restrict__ p1,
    const u16* __restrict__ uxr, const u16* __restrict__ z_in,
    const u16* __restrict__ h_bf,
    const float* __restrict__ g_rph, const float* __restrict__ b_h,
    float* __restrict__ out) {
    __shared__ float sbuf[16];
    int b = blockIdx.x, t = threadIdx.x;
    size_t off = (size_t)b * D + t * 8;
    int cbase = t * 8;

    float wh[8], ux[8], zz[8], hp[8], bh[8], t0[8];
    load_bf8(p0 + off, wh);
    load_bf8(p1 + off, t0);
    #pragma unroll
    for (int i = 0; i < 8; ++i) wh[i] += t0[i];   // K-split partials
    load_bf8(uxr + off, ux);
    load_bf8(z_in + off, zz);
    load_bf8(h_bf + off, hp);
    load_f8(b_h + cbase, bh);

    float s[4] = {0, 0, 0, 0};
    #pragma unroll
    for (int i = 0; i < 8; ++i) {
        s[0] += wh[i] * wh[i]; s[1] += ux[i] * ux[i];
        s[2] += hp[i] * hp[i]; s[3] += bh[i] * bh[i];
    }
    block_sums<4>(s, sbuf);
    float swh = s[0], sux = s[1], shp = s[2], sbh = s[3];

    float cwh, nwh;
    mmm_finish(swh, g_rph[b], &cwh, &nwh);
    #pragma unroll
    for (int i = 0; i < 8; ++i) wh[i] *= cwh;

    // h_tilde = mob_add(mob_add(WhH, UxR), b_h)
    float d = 0.f;
    #pragma unroll
    for (int i = 0; i < 8; ++i) d += wh[i] * ux[i];
    block_sums<1>(&d, sbuf);
    float n1 = mob_apply(wh, ux, nwh * nwh, sux, d);

    d = 0.f;
    #pragma unroll
    for (int i = 0; i < 8; ++i) d += wh[i] * bh[i];
    block_sums<1>(&d, sbuf);
    float nht = mob_apply(wh, bh, n1 * n1, sbh, d);

    // minus = mob_add(-h_proj, h_tilde)
    #pragma unroll
    for (int i = 0; i < 8; ++i) ux[i] = -hp[i];   // reuse ux
    d = 0.f;
    #pragma unroll
    for (int i = 0; i < 8; ++i) d += ux[i] * wh[i];
    block_sums<1>(&d, sbuf);
    float nm = mob_apply(ux, wh, shp, nht * nht, d);

    // emz = exp_map_zero(log_map_zero(minus) * z)
    float lm = artanh_(nm) / nm;
    float sv = 0.f;
    #pragma unroll
    for (int i = 0; i < 8; ++i) {
        float v = lm * ux[i] * zz[i];
        ux[i] = v;
        sv += v * v;
    }
    block_sums<1>(&sv, sbuf);
    float nv = sqrtf(fmaxf(sv, MINN));
    float th = fminf(tanhf(nv), MAXN);
    float ce = th / nv;
    #pragma unroll
    for (int i = 0; i < 8; ++i) ux[i] *= ce;

    // new_h = mob_add(h_proj, emz)
    d = 0.f;
    #pragma unroll
    for (int i = 0; i < 8; ++i) d += hp[i] * ux[i];
    block_sums<1>(&d, sbuf);
    mob_apply(hp, ux, shp, th * th, d);
    store_f8(out + off, hp);
}

// ---------- launch ----------

extern "C" void kernel_launch(void* const* d_in, const int* in_sizes, int n_in,
                              void* d_out, int out_size, void* d_ws, size_t ws_size,
                              hipStream_t stream) {
    const float* hyp_x  = (const float*)d_in[0];
    const float* hidden = (const float*)d_in[1];
    const float* w_z = (const float*)d_in[2];
    const float* w_r = (const float*)d_in[3];
    const float* w_h = (const float*)d_in[4];
    const float* u_z = (const float*)d_in[5];
    const float* u_r = (const float*)d_in[6];
    const float* b_z = (const float*)d_in[7];
    const float* b_r = (const float*)d_in[8];
    const float* b_h = (const float*)d_in[9];
    float* out = (float*)d_out;

    int B = in_sizes[1] / D;   // 2048

    char* ws = (char*)d_ws;
    size_t o = 0;
    auto alloc = [&](size_t bytes) -> void* {
        void* p = ws + o;
        o += (bytes + 255) & ~(size_t)255;
        return p;
    };
    u16* wt[5];   // 0=w_z,1=w_r,2=w_h,3=u_z,4=u_r (transposed bf16 [N][K])
    for (int i = 0; i < 5; ++i) wt[i] = (u16*)alloc((size_t)D * D * 2);
    u16* hx_bf = (u16*)alloc((size_t)B * D * 2);
    u16* h_bf  = (u16*)alloc((size_t)B * D * 2);
    float* g_x   = (float*)alloc((size_t)B * 4);
    float* g_h   = (float*)alloc((size_t)B * 4);
    float* g_rph = (float*)alloc((size_t)B * 4);
    u16* cz0 = (u16*)alloc((size_t)B * D * 2);   // G1 outputs, bf16
    u16* cz1 = (u16*)alloc((size_t)B * D * 2);
    u16* cz2 = (u16*)alloc((size_t)B * D * 2);
    u16* cz3 = (u16*)alloc((size_t)B * D * 2);
    // r7 aliasing (saves ~42 MB of workspace + reset traffic):
    //   mid is in-place: z_buf=cz0, uxr=cz1, rph=cz2 (per-thread slots)
    //   g2 partials reuse dead buffers: p0=cz3 (dead after mid),
    //   p1=hx_bf (dead after g1). Stream order serializes every hazard.
    u16* z_buf = cz0;
    u16* uxr   = cz1;
    u16* rph   = cz2;
    u16* p0    = cz3;
    u16* p1    = hx_bf;

    // K0: transpose all 5 weights (z!=4) + projection (z==4)
    PrepBatch pb;
    pb.W[0] = w_z; pb.Wt[0] = wt[0];
    pb.W[1] = w_r; pb.Wt[1] = wt[1];
    pb.W[2] = u_z; pb.Wt[2] = wt[3];
    pb.W[3] = u_r; pb.Wt[3] = wt[4];
    pb.W[4] = w_h; pb.Wt[4] = wt[2];
    pb.hx = hyp_x; pb.h = hidden;
    pb.hx_bf = hx_bf; pb.h_bf = h_bf;
    pb.g_x = g_x; pb.g_h = g_h;
    wtrans_prep<<<dim3(D / 64, D / 64, 6), 256, 0, stream>>>(pb);

    // G1: 4 GEMMs, 256x256 tiles, 8 waves (256 wgs = 1/CU)
    G1Batch g1;
    g1.A[0] = h_bf;  g1.W[0] = wt[0]; g1.C[0] = cz0;
    g1.A[1] = hx_bf; g1.W[1] = wt[3]; g1.C[1] = cz1;
    g1.A[2] = h_bf;  g1.W[2] = wt[1]; g1.C[2] = cz2;
    g1.A[3] = hx_bf; g1.W[3] = wt[4]; g1.C[3] = cz3;
    g1_kernel<<<dim3(D / 256, B / 256, 4), 512, 0, stream>>>(g1);

    // K4: middle fusion (in-place on cz0/cz1/cz2)
    mid_kernel<<<dim3(B), 256, 0, stream>>>(cz0, cz1, cz2, cz3, h_bf, g_x, g_h,
                                            b_z, b_r, z_buf, uxr, rph, g_rph);

    // G2: 2-way K-split r_point_h @ w_h -> bf16 partials p0,p1
    //     256x128 tiles so the split still fills all 256 CUs
    GemmBatch g2;
    g2.A[0] = rph; g2.W[0] = wt[2]; g2.C[0] = p0; g2.koff[0] = 0;
    g2.A[1] = rph; g2.W[1] = wt[2]; g2.C[1] = p1; g2.koff[1] = 1024;
    g2_kernel<<<dim3(D / 128, B / 256, 2), 512, 0, stream>>>(g2);

    // K6: epilogue (sums the two K-partials of Wh @ r_point_h)
    fin_kernel<<<dim3(B), 256, 0, stream>>>(p0, p1, uxr, z_buf, h_bf,
                                            g_rph, b_h, out);
}

// Round 8
// 293.296 us; speedup vs baseline: 1.0552x; 1.0121x over previous
//
#include <hip/hip_runtime.h>
#include <hip/hip_bf16.h>
#include <math.h>

#define EPS 1e-5f
#define MAXN (1.0f - EPS)
#define MINN 1e-10f

constexpr int D = 2048;      // Dh == Din == 2048 for this problem

typedef unsigned short u16;
typedef __bf16 bf16x8 __attribute__((ext_vector_type(8)));
typedef float floatx4 __attribute__((ext_vector_type(4)));

// ---------- small helpers ----------

__device__ __forceinline__ u16 f2bf(float f) {
    union { float f; unsigned u; } v; v.f = f;
    unsigned r = v.u + 0x7FFFu + ((v.u >> 16) & 1u);   // RNE
    return (u16)(r >> 16);
}

__device__ __forceinline__ float bf2f(u16 b) {
    union { unsigned u; float f; } v; v.u = ((unsigned)b) << 16; return v.f;
}

// load 8 contiguous bf16 -> float[8] (one 16B load)
__device__ __forceinline__ void load_bf8(const u16* p, float* d) {
    uint4 r = *(const uint4*)p;
    unsigned w[4] = {r.x, r.y, r.z, r.w};
    #pragma unroll
    for (int i = 0; i < 4; ++i) {
        d[2 * i]     = bf2f((u16)(w[i] & 0xFFFFu));
        d[2 * i + 1] = bf2f((u16)(w[i] >> 16));
    }
}

// store float[8] -> 8 contiguous bf16 (one 16B store)
__device__ __forceinline__ void store_bf8(u16* p, const float* s) {
    u16 pk[8];
    #pragma unroll
    for (int i = 0; i < 8; ++i) pk[i] = f2bf(s[i]);
    *(uint4*)p = *(const uint4*)pk;
}

__device__ __forceinline__ void load_f8(const float* p, float* d) {
    *(float4*)(d)     = *(const float4*)(p);
    *(float4*)(d + 4) = *(const float4*)(p + 4);
}

__device__ __forceinline__ void store_f8(float* p, const float* s) {
    *(float4*)(p)     = *(const float4*)(s);
    *(float4*)(p + 4) = *(const float4*)(s + 4);
}

__device__ __forceinline__ float artanh_(float x) {
    x = fminf(fmaxf(x, -1.0f + EPS), 1.0f - EPS);
    return 0.5f * logf((1.0f + x) / (1.0f - x));
}

__device__ __forceinline__ float sigmoid_(float x) {
    return 1.0f / (1.0f + expf(-x));
}

// async global->LDS, 16 bytes/lane; lds base must be wave-uniform
__device__ __forceinline__ void gl_lds16(const u16* g, u16* l) {
    __builtin_amdgcn_global_load_lds(
        (const __attribute__((address_space(1))) unsigned int*)g,
        (__attribute__((address_space(3))) unsigned int*)l, 16, 0, 0);
}

// N simultaneous block-wide sums, ONE barrier pair. 256 threads / 4 waves.
template<int N>
__device__ __forceinline__ void block_sums(float* v, float* sbuf) {
    #pragma unroll
    for (int n = 0; n < N; ++n)
        #pragma unroll
        for (int off = 32; off >= 1; off >>= 1) v[n] += __shfl_xor(v[n], off, 64);
    int w = threadIdx.x >> 6;
    __syncthreads();                       // protect sbuf from previous call
    if ((threadIdx.x & 63) == 0) {
        #pragma unroll
        for (int n = 0; n < N; ++n) sbuf[w * N + n] = v[n];
    }
    __syncthreads();
    #pragma unroll
    for (int n = 0; n < N; ++n)
        v[n] = sbuf[n] + sbuf[N + n] + sbuf[2 * N + n] + sbuf[3 * N + n];
}

// finish mob_mat_mul: given |Mx|^2 and g = artanh(x_n)/x_n, return scale coef
// (out = coef * Mx_raw) and the output norm (post-proj).
__device__ __forceinline__ void mmm_finish(float sum2, float g, float* coef, float* onorm) {
    float mxn = sqrtf(fmaxf(sum2, MINN));
    float tt  = tanhf(mxn * g);
    float on  = fminf(tt, MAXN);
    *coef = on / mxn;
    *onorm = on;
}

// apply mob_add given duv already reduced. |num|^2 computed ANALYTICALLY:
// |cu*u + cv*v|^2 = cu^2 u2 + 2 cu cv duv + cv^2 v2  (no second reduction).
// u <- proj(mob_add(u,v)); returns post-proj norm.
__device__ __forceinline__ float mob_apply(float* u, const float* v,
                                           float u2, float v2, float duv) {
    float cu  = 1.f + 2.f * duv + v2;
    float cv  = 1.f - u2;
    float den = fmaxf(1.f + 2.f * duv + u2 * v2, MINN);
    float s2  = cu * cu * u2 + 2.f * cu * cv * duv + cv * cv * v2;
    float n   = sqrtf(fmaxf(s2 / (den * den), MINN));
    float sc  = ((n > MAXN) ? MAXN / n : 1.f) / den;
    #pragma unroll
    for (int i = 0; i < 8; ++i) u[i] = sc * (cu * u[i] + cv * v[i]);
    return fminf(n, MAXN);
}

// shared transpose-tile helper: one 64x64 f32->bf16T tile through LDS
__device__ __forceinline__ void trans_tile(const float* W, u16* Wt,
                                           int n0, int k0, float* tile) {
    int t = threadIdx.x;
    int lr = t >> 4, lc = (t & 15) * 4;
    #pragma unroll
    for (int p = 0; p < 4; ++p) {
        int r = lr + p * 16;
        float4 v = *(const float4*)(W + (size_t)(k0 + r) * D + n0 + lc);
        tile[r * 65 + lc + 0] = v.x;
        tile[r * 65 + lc + 1] = v.y;
        tile[r * 65 + lc + 2] = v.z;
        tile[r * 65 + lc + 3] = v.w;
    }
    __syncthreads();
    int wn = t >> 3, ws = (t & 7) * 8;
    #pragma unroll
    for (int p = 0; p < 2; ++p) {
        int n = wn + p * 32;
        u16 pk[8];
        #pragma unroll
        for (int j = 0; j < 8; ++j) pk[j] = f2bf(tile[(ws + j) * 65 + n]);
        *(uint4*)(Wt + (size_t)(n0 + n) * D + k0 + ws) = *(uint4*)pk;
    }
}

// ---------- K0: transpose 5 weights (z!=4) + input projection (z==4) ----------

struct PrepBatch {
    const float* W[5]; u16* Wt[5];
    const float* hx; const float* h;
    u16* hx_bf; u16* h_bf;
    float* g_x; float* g_h;
};

__global__ __launch_bounds__(256) void wtrans_prep(PrepBatch pb) {
    __shared__ float tile[64 * 65];        // transpose tile; first 8 reused as sbuf
    int t = threadIdx.x;

    if (blockIdx.z != 4) {
        int wi = (blockIdx.z == 5) ? 4 : blockIdx.z;
        trans_tile(pb.W[wi], pb.Wt[wi],
                   blockIdx.x * 64, blockIdx.y * 64, tile);
    } else {
        // projection: 1024 blocks here, each handles 2 rows
        int bid = blockIdx.y * (D / 64) + blockIdx.x;   // 0..1023
        for (int rr = 0; rr < 2; ++rr) {
            int b = bid * 2 + rr;
            size_t off = (size_t)b * D + t * 8;
            float xv[8], hv[8];
            load_f8(pb.hx + off, xv);
            load_f8(pb.h + off, hv);
            float s[2] = {0.f, 0.f};
            #pragma unroll
            for (int i = 0; i < 8; ++i) { s[0] += xv[i] * xv[i]; s[1] += hv[i] * hv[i]; }
            block_sums<2>(s, tile);

            float nx = sqrtf(fmaxf(s[0], MINN));
            float scx = (nx > MAXN) ? MAXN / nx : 1.0f;
            float nh = sqrtf(fmaxf(s[1], MINN));
            float sch = (nh > MAXN) ? MAXN / nh : 1.0f;
            #pragma unroll
            for (int i = 0; i < 8; ++i) { xv[i] *= scx; hv[i] *= sch; }
            store_bf8(pb.hx_bf + off, xv);
            store_bf8(pb.h_bf + off, hv);
            if (t == 0) {
                float xn = fminf(nx, MAXN), hn = fminf(nh, MAXN);
                pb.g_x[b] = artanh_(xn) / xn;
                pb.g_h[b] = artanh_(hn) / hn;
            }
        }
    }
}

// ---------- 256-wide GEMM core (r8: merged 2-phase schedule) ----------
// C[M,N](bf16) = A[M,K](bf16) @ W[N,K](bf16)^T.
// BM=256, BN = NJ*64 (NJ=4 -> 256, NJ=2 -> 128), BK=64 split into two
// 32-k half-units. LDS ring: {2 buf} x {2 khalf} per operand.
// 512 threads = 8 waves (2M x 4N), per-wave output 128 x NJ*16.
// r8 change: NJ=4 path merged from 4 phases to 2 (the NJ=2 path was
// already 2-phase). Phase = {12 ds_reads (8 A-frags + NJ B-frags);
// stage A+B; BAR; setprio1; 8*NJ MFMA; setprio0; BAR}. Barriers/K-tile
// 9 -> 5. Reads/tile unchanged (24 b128); compiler-managed fine-grained
// lgkmcnt before each MFMA (r5 result: explicit lgkm0+schedbar serializes
// pipes, do not reintroduce). Counted vmcnt(4|3) once per tile, never 0.
// Ledger (NJ=4, 4 loads/stage-pair, 8/tile): residue at tile start =
// k0(t+1) [4]; ph0 issues k1(t+1) [4], ph1 issues k0(t+2) [4] -> 12
// outstanding; boundary vmcnt(4) completes k0(t+1)+k1(t+1), leaves
// k0(t+2). WAR: ph1's re-stage of (bsel,kh0) issues after ph0's END
// barrier, which postdates all waves' kk0 consumption.
// Swizzle (verified 0 SQ_LDS_BANK_CONFLICT): LDS slot s holds kseg
// s^((row>>1)&3); pre-swizzled global source, swizzled ds_read, linear
// gl_lds dest. NOTE (r1/r4 errata): s = quad^(row&3) and the 32x32
// fragment geometry both produce 6.3M conflicts — do not regress to them.

#define PHASE_MID() do { \
    __builtin_amdgcn_s_barrier(); \
    __builtin_amdgcn_s_setprio(1); } while (0)

#define PHASE_END() do { \
    __builtin_amdgcn_s_setprio(0); \
    __builtin_amdgcn_s_barrier(); } while (0)

template<int KLEN, int NJ>
__device__ __forceinline__ void gemm256_body(const u16* __restrict__ A,
                                             const u16* __restrict__ W,
                                             u16* __restrict__ C, int koff,
                                             u16* As, u16* Ws) {
    constexpr int T  = KLEN / 64;       // K-tiles
    constexpr int BN = NJ * 64;
    constexpr int AU = 8192;            // u16 per A half-unit (256 rows x 32 k)
    constexpr int BU = BN * 32;         // u16 per B half-unit

    int t0 = threadIdx.x;
    int wave = t0 >> 6, lane = t0 & 63, l16 = lane & 15, quad = lane >> 4;
    int wr = wave >> 2, wc = wave & 3;      // 2x4 wave grid
    int brow = blockIdx.y * 256, bcol = blockIdx.x * BN;

    // staging source (per-thread, pre-swizzled k-segment)
    int srow = t0 >> 2;                     // 0..127 per issue
    int sseg = (t0 & 3) ^ ((srow >> 1) & 3);
    const u16* srcA = A + (size_t)(brow + srow) * D + koff + sseg * 8;
    const u16* srcB = W + (size_t)(bcol + srow) * D + koff + sseg * 8;
    u16* ldsA = As + wave * 512;            // wave-uniform slices
    u16* ldsB = Ws + wave * 512;

    auto stageA = [&](int buf, int kh, int tile) {
        const u16* s = srcA + tile * 64 + kh * 32;
        u16* d = ldsA + (buf * 2 + kh) * AU;
        gl_lds16(s, d);
        gl_lds16(s + (size_t)128 * D, d + 4096);
    };
    auto stageB = [&](int buf, int kh, int tile) {
        const u16* s = srcB + tile * 64 + kh * 32;
        u16* d = ldsB + (buf * 2 + kh) * BU;
        gl_lds16(s, d);
        if constexpr (NJ == 4) gl_lds16(s + (size_t)128 * D, d + 4096);
    };

    // fragment-read bases (swizzled); frag (buf,kk,i): +(buf*2+kk)*AU + i*512
    const u16* aF = As + (wr * 128 + l16) * 32 + ((quad ^ ((l16 >> 1) & 3)) * 8);
    const u16* bF = Ws + (wc * (NJ * 16) + l16) * 32 + ((quad ^ ((l16 >> 1) & 3)) * 8);

    floatx4 acc[8][NJ];
    #pragma unroll
    for (int i = 0; i < 8; ++i)
        #pragma unroll
        for (int j = 0; j < NJ; ++j)
            #pragma unroll
            for (int e = 0; e < 4; ++e) acc[i][j][e] = 0.f;

    // prologue: tile0 complete + tile1 khalf0; wait so tile0 landed
    stageA(0, 0, 0); stageB(0, 0, 0);
    stageA(0, 1, 0); stageB(0, 1, 0);
    stageA(1, 0, 1); stageB(1, 0, 1);
    if constexpr (NJ == 4) asm volatile("s_waitcnt vmcnt(4)" ::: "memory");
    else                   asm volatile("s_waitcnt vmcnt(3)" ::: "memory");
    __builtin_amdgcn_s_barrier();

    #pragma unroll 2
    for (int tt = 0; tt < T; ++tt) {
        int bsel = tt & 1, bno = bsel ^ 1;
        const u16* aT = aF + bsel * (2 * AU);
        const u16* bT = bF + bsel * (2 * BU);
        bool st1 = (tt + 1) < T, st2 = (tt + 2) < T;

        bf16x8 bfr[NJ], afr[8];
        // ---- phase 0: kk=0 (all 8 row-frags + NJ B-frags) ----
        #pragma unroll
        for (int j = 0; j < NJ; ++j) bfr[j] = *(const bf16x8*)(bT + j * 512);
        #pragma unroll
        for (int i = 0; i < 8; ++i) afr[i] = *(const bf16x8*)(aT + i * 512);
        if (st1) { stageA(bno, 1, tt + 1); stageB(bno, 1, tt + 1); }
        PHASE_MID();
        #pragma unroll
        for (int i = 0; i < 8; ++i)
            #pragma unroll
            for (int j = 0; j < NJ; ++j)
                acc[i][j] = __builtin_amdgcn_mfma_f32_16x16x32_bf16(afr[i], bfr[j], acc[i][j], 0, 0, 0);
        PHASE_END();
        // ---- phase 1: kk=1; tile boundary ----
        #pragma unroll
        for (int j = 0; j < NJ; ++j) bfr[j] = *(const bf16x8*)(bT + BU + j * 512);
        #pragma unroll
        for (int i = 0; i < 8; ++i) afr[i] = *(const bf16x8*)(aT + AU + i * 512);
        if (st2) { stageA(bsel, 0, tt + 2); stageB(bsel, 0, tt + 2); }
        PHASE_MID();
        #pragma unroll
        for (int i = 0; i < 8; ++i)
            #pragma unroll
            for (int j = 0; j < NJ; ++j)
                acc[i][j] = __builtin_amdgcn_mfma_f32_16x16x32_bf16(afr[i], bfr[j], acc[i][j], 0, 0, 0);
        __builtin_amdgcn_s_setprio(0);
        if constexpr (NJ == 4) asm volatile("s_waitcnt vmcnt(4)" ::: "memory");
        else                   asm volatile("s_waitcnt vmcnt(3)" ::: "memory");
        __builtin_amdgcn_s_barrier();
    }

    // epilogue: C layout col=lane&15, row=(lane>>4)*4+reg (16x16x32 bf16)
    #pragma unroll
    for (int i = 0; i < 8; ++i) {
        #pragma unroll
        for (int j = 0; j < NJ; ++j) {
            int row = brow + wr * 128 + i * 16 + quad * 4;
            int col = bcol + wc * (NJ * 16) + j * 16 + l16;
            #pragma unroll
            for (int r = 0; r < 4; ++r)
                C[(size_t)(row + r) * D + col] = f2bf(acc[i][j][r]);
        }
    }
}

// ---------- G1: 4 GEMMs (256x256 tiles) ----------

struct G1Batch { const u16* A[4]; const u16* W[4]; u16* C[4]; };

__global__ __launch_bounds__(512, 2) void g1_kernel(G1Batch gb) {
    __shared__ u16 As[32768];              // 64 KB
    __shared__ u16 Ws[32768];              // 64 KB  (128 KB total)
    int z = blockIdx.z;
    gemm256_body<2048, 4>(gb.A[z], gb.W[z], gb.C[z], 0, As, Ws);
}

// ---------- G2: 2-way K-split GEMM (256x128 tiles) ----------

struct GemmBatch { const u16* A[2]; const u16* W[2]; u16* C[2]; int koff[2]; };

__global__ __launch_bounds__(512, 2) void g2_kernel(GemmBatch gb) {
    __shared__ u16 As[32768];              // 64 KB
    __shared__ u16 Ws[16384];              // 32 KB  (96 KB total)
    int z = blockIdx.z;
    gemm256_body<1024, 2>(gb.A[z], gb.W[z], gb.C[z], gb.koff[z], As, Ws);
}

// ---------- K4: fused middle (finish 4 matvecs, z, r, r_point_h) ----------
// outputs ALIAS inputs (z_out==c_wz, uxr_out==c_uz, rph_bf==c_wr).
// Safe: each thread loads all its inputs into registers before its first
// barrier; every store targets exactly the 8-element slot that only this
// thread read.

__global__ __launch_bounds__(256) void mid_kernel(
    const u16* __restrict__ c_wz, const u16* __restrict__ c_uz,
    const u16* __restrict__ c_wr, const u16* __restrict__ c_ur,
    const u16* __restrict__ h_bf,
    const float* __restrict__ g_x, const float* __restrict__ g_h,
    const float* __restrict__ b_z, const float* __restrict__ b_r,
    u16* __restrict__ z_out, u16* __restrict__ uxr_out,
    u16* __restrict__ rph_bf, float* __restrict__ g_rph) {
    __shared__ float sbuf[24];
    int b = blockIdx.x, t = threadIdx.x;
    size_t off = (size_t)b * D + t * 8;
    int cbase = t * 8;

    float wz[8], uz[8], wr2[8], ur2[8], hp[8], bz[8], br[8];
    load_bf8(c_wz + off, wz);
    load_bf8(c_uz + off, uz);
    load_bf8(c_wr + off, wr2);
    load_bf8(c_ur + off, ur2);
    load_bf8(h_bf + off, hp);
    load_f8(b_z + cbase, bz);
    load_f8(b_r + cbase, br);

    float s[6] = {0, 0, 0, 0, 0, 0};
    #pragma unroll
    for (int i = 0; i < 8; ++i) {
        s[0] += wz[i] * wz[i];  s[1] += uz[i] * uz[i];
        s[2] += wr2[i] * wr2[i]; s[3] += ur2[i] * ur2[i];
        s[4] += bz[i] * bz[i];  s[5] += br[i] * br[i];
    }
    block_sums<6>(s, sbuf);
    float gh = g_h[b], gx = g_x[b];

    float cwz, nwz, cuz, nuz, cwr, nwr, cur, nur;
    mmm_finish(s[0], gh, &cwz, &nwz);
    mmm_finish(s[1], gx, &cuz, &nuz);
    mmm_finish(s[2], gh, &cwr, &nwr);
    mmm_finish(s[3], gx, &cur, &nur);
    #pragma unroll
    for (int i = 0; i < 8; ++i) {
        wz[i] *= cwz; uz[i] *= cuz; wr2[i] *= cwr; ur2[i] *= cur;
    }
    float sbz = s[4], sbr2 = s[5];

    // z-chain and r-chain mob_add #1 (batched duv)
    float d[2] = {0.f, 0.f};
    #pragma unroll
    for (int i = 0; i < 8; ++i) { d[0] += wz[i] * uz[i]; d[1] += wr2[i] * ur2[i]; }
    block_sums<2>(d, sbuf);
    float n1z = mob_apply(wz, uz, nwz * nwz, nuz * nuz, d[0]);
    float n1r = mob_apply(wr2, ur2, nwr * nwr, nur * nur, d[1]);

    // mob_add #2 (+bias, batched duv)
    d[0] = 0.f; d[1] = 0.f;
    #pragma unroll
    for (int i = 0; i < 8; ++i) { d[0] += wz[i] * bz[i]; d[1] += wr2[i] * br[i]; }
    block_sums<2>(d, sbuf);
    float n2z = mob_apply(wz, bz, n1z * n1z, sbz, d[0]);
    float n2r = mob_apply(wr2, br, n1r * n1r, sbr2, d[1]);

    float gz = artanh_(n2z) / n2z;
    float gr = artanh_(n2r) / n2r;
    float zz[8], v[8];
    float sv = 0.f;
    #pragma unroll
    for (int i = 0; i < 8; ++i) {
        zz[i] = sigmoid_(gz * wz[i]);
        float r = sigmoid_(gr * wr2[i]);
        v[i] = gh * hp[i] * r;            // log_map_zero(h) * r
        sv += v[i] * v[i];
    }
    store_bf8(z_out + off, zz);
    block_sums<1>(&sv, sbuf);
    float nv = sqrtf(fmaxf(sv, MINN));
    float th = fminf(tanhf(nv), MAXN);
    float cr = th / nv;
    #pragma unroll
    for (int i = 0; i < 8; ++i) v[i] *= cr;
    store_bf8(rph_bf + off, v);
    store_bf8(uxr_out + off, ur2);        // finished UxR (reused for h_tilde)
    if (t == 0) g_rph[b] = artanh_(th) / th;
}

// ---------- K6: epilogue ----------

__global__ __launch_bounds__(256) void fin_kernel(
    const u16* __restrict__ p0, const u16* __restrict__ p1,
    const u16* __restrict__ uxr, const u16* __restrict__ z_in,
    const u16* __restrict__ h_bf,
    const float* __restrict__ g_rph, const float* __restrict__ b_h,
    float* __restrict__ out) {
    __shared__ float sbuf[16];
    int b = blockIdx.x, t = threadIdx.x;
    size_t off = (size_t)b * D + t * 8;
    int cbase = t * 8;

    float wh[8], ux[8], zz[8], hp[8], bh[8], t0[8];
    load_bf8(p0 + off, wh);
    load_bf8(p1 + off, t0);
    #pragma unroll
    for (int i = 0; i < 8; ++i) wh[i] += t0[i];   // K-split partials
    load_bf8(uxr + off, ux);
    load_bf8(z_in + off, zz);
    load_bf8(h_bf + off, hp);
    load_f8(b_h + cbase, bh);

    float s[4] = {0, 0, 0, 0};
    #pragma unroll
    for (int i = 0; i < 8; ++i) {
        s[0] += wh[i] * wh[i]; s[1] += ux[i] * ux[i];
        s[2] += hp[i] * hp[i]; s[3] += bh[i] * bh[i];
    }
    block_sums<4>(s, sbuf);
    float swh = s[0], sux = s[1], shp = s[2], sbh = s[3];

    float cwh, nwh;
    mmm_finish(swh, g_rph[b], &cwh, &nwh);
    #pragma unroll
    for (int i = 0; i < 8; ++i) wh[i] *= cwh;

    // h_tilde = mob_add(mob_add(WhH, UxR), b_h)
    float d = 0.f;
    #pragma unroll
    for (int i = 0; i < 8; ++i) d += wh[i] * ux[i];
    block_sums<1>(&d, sbuf);
    float n1 = mob_apply(wh, ux, nwh * nwh, sux, d);

    d = 0.f;
    #pragma unroll
    for (int i = 0; i < 8; ++i) d += wh[i] * bh[i];
    block_sums<1>(&d, sbuf);
    float nht = mob_apply(wh, bh, n1 * n1, sbh, d);

    // minus = mob_add(-h_proj, h_tilde)
    #pragma unroll
    for (int i = 0; i < 8; ++i) ux[i] = -hp[i];   // reuse ux
    d = 0.f;
    #pragma unroll
    for (int i = 0; i < 8; ++i) d += ux[i] * wh[i];
    block_sums<1>(&d, sbuf);
    float nm = mob_apply(ux, wh, shp, nht * nht, d);

    // emz = exp_map_zero(log_map_zero(minus) * z)
    float lm = artanh_(nm) / nm;
    float sv = 0.f;
    #pragma unroll
    for (int i = 0; i < 8; ++i) {
        float v = lm * ux[i] * zz[i];
        ux[i] = v;
        sv += v * v;
    }
    block_sums<1>(&sv, sbuf);
    float nv = sqrtf(fmaxf(sv, MINN));
    float th = fminf(tanhf(nv), MAXN);
    float ce = th / nv;
    #pragma unroll
    for (int i = 0; i < 8; ++i) ux[i] *= ce;

    // new_h = mob_add(h_proj, emz)
    d = 0.f;
    #pragma unroll
    for (int i = 0; i < 8; ++i) d += hp[i] * ux[i];
    block_sums<1>(&d, sbuf);
    mob_apply(hp, ux, shp, th * th, d);
    store_f8(out + off, hp);
}

// ---------- launch ----------

extern "C" void kernel_launch(void* const* d_in, const int* in_sizes, int n_in,
                              void* d_out, int out_size, void* d_ws, size_t ws_size,
                              hipStream_t stream) {
    const float* hyp_x  = (const float*)d_in[0];
    const float* hidden = (const float*)d_in[1];
    const float* w_z = (const float*)d_in[2];
    const float* w_r = (const float*)d_in[3];
    const float* w_h = (const float*)d_in[4];
    const float* u_z = (const float*)d_in[5];
    const float* u_r = (const float*)d_in[6];
    const float* b_z = (const float*)d_in[7];
    const float* b_r = (const float*)d_in[8];
    const float* b_h = (const float*)d_in[9];
    float* out = (float*)d_out;

    int B = in_sizes[1] / D;   // 2048

    char* ws = (char*)d_ws;
    size_t o = 0;
    auto alloc = [&](size_t bytes) -> void* {
        void* p = ws + o;
        o += (bytes + 255) & ~(size_t)255;
        return p;
    };
    u16* wt[5];   // 0=w_z,1=w_r,2=w_h,3=u_z,4=u_r (transposed bf16 [N][K])
    for (int i = 0; i < 5; ++i) wt[i] = (u16*)alloc((size_t)D * D * 2);
    u16* hx_bf = (u16*)alloc((size_t)B * D * 2);
    u16* h_bf  = (u16*)alloc((size_t)B * D * 2);
    float* g_x   = (float*)alloc((size_t)B * 4);
    float* g_h   = (float*)alloc((size_t)B * 4);
    float* g_rph = (float*)alloc((size_t)B * 4);
    u16* cz0 = (u16*)alloc((size_t)B * D * 2);   // G1 outputs, bf16
    u16* cz1 = (u16*)alloc((size_t)B * D * 2);
    u16* cz2 = (u16*)alloc((size_t)B * D * 2);
    u16* cz3 = (u16*)alloc((size_t)B * D * 2);
    // aliasing (saves ~42 MB of workspace + reset traffic):
    //   mid is in-place: z_buf=cz0, uxr=cz1, rph=cz2 (per-thread slots)
    //   g2 partials reuse dead buffers: p0=cz3 (dead after mid),
    //   p1=hx_bf (dead after g1). Stream order serializes every hazard.
    u16* z_buf = cz0;
    u16* uxr   = cz1;
    u16* rph   = cz2;
    u16* p0    = cz3;
    u16* p1    = hx_bf;

    // K0: transpose all 5 weights (z!=4) + projection (z==4)
    PrepBatch pb;
    pb.W[0] = w_z; pb.Wt[0] = wt[0];
    pb.W[1] = w_r; pb.Wt[1] = wt[1];
    pb.W[2] = u_z; pb.Wt[2] = wt[3];
    pb.W[3] = u_r; pb.Wt[3] = wt[4];
    pb.W[4] = w_h; pb.Wt[4] = wt[2];
    pb.hx = hyp_x; pb.h = hidden;
    pb.hx_bf = hx_bf; pb.h_bf = h_bf;
    pb.g_x = g_x; pb.g_h = g_h;
    wtrans_prep<<<dim3(D / 64, D / 64, 6), 256, 0, stream>>>(pb);

    // G1: 4 GEMMs, 256x256 tiles, 8 waves (256 wgs = 1/CU)
    G1Batch g1;
    g1.A[0] = h_bf;  g1.W[0] = wt[0]; g1.C[0] = cz0;
    g1.A[1] = hx_bf; g1.W[1] = wt[3]; g1.C[1] = cz1;
    g1.A[2] = h_bf;  g1.W[2] = wt[1]; g1.C[2] = cz2;
    g1.A[3] = hx_bf; g1.W[3] = wt[4]; g1.C[3] = cz3;
    g1_kernel<<<dim3(D / 256, B / 256, 4), 512, 0, stream>>>(g1);

    // K4: middle fusion (in-place on cz0/cz1/cz2)
    mid_kernel<<<dim3(B), 256, 0, stream>>>(cz0, cz1, cz2, cz3, h_bf, g_x, g_h,
                                            b_z, b_r, z_buf, uxr, rph, g_rph);

    // G2: 2-way K-split r_point_h @ w_h -> bf16 partials p0,p1
    //     256x128 tiles so the split still fills all 256 CUs
    GemmBatch g2;
    g2.A[0] = rph; g2.W[0] = wt[2]; g2.C[0] = p0; g2.koff[0] = 0;
    g2.A[1] = rph; g2.W[1] = wt[2]; g2.C[1] = p1; g2.koff[1] = 1024;
    g2_kernel<<<dim3(D / 128, B / 256, 2), 512, 0, stream>>>(g2);

    // K6: epilogue (sums the two K-partials of Wh @ r_point_h)
    fin_kernel<<<dim3(B), 256, 0, stream>>>(p0, p1, uxr, z_buf, h_bf,
                                            g_rph, b_h, out);
}